// Round 1
// baseline (5436.493 us; speedup 1.0000x reference)
//
#include <hip/hip_runtime.h>

#define D 128

// C[M,NC] = act( A[M,128] @ W[NC,128]^T + bias )
// 64x64 tile per block, 256 threads, 4x4 register tile per thread.
// LDS: XOR-swizzled [64][128] fp32 tiles for A and W (65536 B total -> 2 blocks/CU).
__global__ __launch_bounds__(256, 2)
void gemm_k128(const float* __restrict__ A, const float* __restrict__ W,
               const float* __restrict__ bias, float* __restrict__ C,
               int M, int NC, int reluA, int reluC)
{
    __shared__ float sA[64 * 128];
    __shared__ float sW[64 * 128];
    const int t  = threadIdx.x;
    const int m0 = blockIdx.x * 64;
    const int n0 = blockIdx.y * 64;

    // ---- stage A tile (64 rows x 128 k), zero-fill OOB rows, optional relu ----
    {
        const int c4 = (t & 31) * 4;   // k base 0..124
        const int r  = t >> 5;         // 0..7
        #pragma unroll
        for (int i = 0; i < 8; ++i) {
            const int rr = r * 8 + i;  // 0..63
            const int gm = m0 + rr;
            float4 v = make_float4(0.f, 0.f, 0.f, 0.f);
            if (gm < M) v = *reinterpret_cast<const float4*>(A + (size_t)gm * D + c4);
            if (reluA) { v.x = fmaxf(v.x, 0.f); v.y = fmaxf(v.y, 0.f);
                         v.z = fmaxf(v.z, 0.f); v.w = fmaxf(v.w, 0.f); }
            const int cb = c4 ^ ((rr & 7) << 2);   // swizzled column base (multiple of 4)
            sA[rr * 128 + cb + 0] = v.x;
            sA[rr * 128 + cb + 1] = v.y;
            sA[rr * 128 + cb + 2] = v.z;
            sA[rr * 128 + cb + 3] = v.w;
        }
        #pragma unroll
        for (int i = 0; i < 8; ++i) {
            const int rr = r * 8 + i;
            float4 v = *reinterpret_cast<const float4*>(W + (size_t)(n0 + rr) * D + c4);
            const int cb = c4 ^ ((rr & 7) << 2);
            sW[rr * 128 + cb + 0] = v.x;
            sW[rr * 128 + cb + 1] = v.y;
            sW[rr * 128 + cb + 2] = v.z;
            sW[rr * 128 + cb + 3] = v.w;
        }
    }
    __syncthreads();

    const int tx = t & 15;   // -> cols tx + 16*j
    const int ty = t >> 4;   // -> rows ty + 16*i
    const int axor = (ty & 7) << 2;   // rows ty+16i share (row&7)
    const int wxor = (tx & 7) << 2;

    float acc[4][4];
    #pragma unroll
    for (int i = 0; i < 4; ++i)
        #pragma unroll
        for (int j = 0; j < 4; ++j) acc[i][j] = 0.f;

    #pragma unroll 8
    for (int k = 0; k < D; ++k) {
        const int kA = k ^ axor;
        const int kW = k ^ wxor;
        float a0 = sA[(ty     ) * 128 + kA];
        float a1 = sA[(ty + 16) * 128 + kA];
        float a2 = sA[(ty + 32) * 128 + kA];
        float a3 = sA[(ty + 48) * 128 + kA];
        float w0 = sW[(tx     ) * 128 + kW];
        float w1 = sW[(tx + 16) * 128 + kW];
        float w2 = sW[(tx + 32) * 128 + kW];
        float w3 = sW[(tx + 48) * 128 + kW];
        acc[0][0] += a0 * w0; acc[0][1] += a0 * w1; acc[0][2] += a0 * w2; acc[0][3] += a0 * w3;
        acc[1][0] += a1 * w0; acc[1][1] += a1 * w1; acc[1][2] += a1 * w2; acc[1][3] += a1 * w3;
        acc[2][0] += a2 * w0; acc[2][1] += a2 * w1; acc[2][2] += a2 * w2; acc[2][3] += a2 * w3;
        acc[3][0] += a3 * w0; acc[3][1] += a3 * w1; acc[3][2] += a3 * w2; acc[3][3] += a3 * w3;
    }

    float bv[4] = {0.f, 0.f, 0.f, 0.f};
    if (bias) {
        bv[0] = bias[n0 + tx];      bv[1] = bias[n0 + tx + 16];
        bv[2] = bias[n0 + tx + 32]; bv[3] = bias[n0 + tx + 48];
    }
    #pragma unroll
    for (int i = 0; i < 4; ++i) {
        const int gm = m0 + ty + 16 * i;
        if (gm < M) {
            #pragma unroll
            for (int j = 0; j < 4; ++j) {
                float v = acc[i][j] + bv[j];
                if (reluC) v = fmaxf(v, 0.f);
                C[(size_t)gm * NC + n0 + tx + 16 * j] = v;
            }
        }
    }
}

// agg[dst[e]] += m[src[e]] for all edges; 32 threads per edge, 4 floats each.
__global__ __launch_bounds__(256)
void scatter_add(const float* __restrict__ m, const int* __restrict__ src,
                 const int* __restrict__ dst, float* __restrict__ agg,
                 int E, int N)
{
    const int tid  = blockIdx.x * 256 + threadIdx.x;
    const int e    = tid >> 5;
    const int lane = tid & 31;
    if (e >= E) return;
    const int s = src[e];
    const int d = dst[e];
    if ((unsigned)s >= (unsigned)N || (unsigned)d >= (unsigned)N) return;  // guard bad indices
    float4 v = *reinterpret_cast<const float4*>(m + (size_t)s * D + lane * 4);
    float* o = agg + (size_t)d * D + lane * 4;
    atomicAdd(o + 0, v.x);
    atomicAdd(o + 1, v.y);
    atomicAdd(o + 2, v.z);
    atomicAdd(o + 3, v.w);
}

// h = GRU(agg, h) elementwise combine from precomputed gi (g1) and gh (g2), torch gate order r,z,n.
__global__ __launch_bounds__(256)
void gru_combine(const float* __restrict__ g1, const float* __restrict__ g2,
                 float* __restrict__ h, int total)
{
    const int tid = blockIdx.x * 256 + threadIdx.x;
    if (tid >= total) return;
    const int node = tid >> 7;     // /128
    const int c    = tid & 127;
    const size_t b = (size_t)node * 384 + c;
    const float ir = g1[b], iz = g1[b + 128], in = g1[b + 256];
    const float hr = g2[b], hz = g2[b + 128], hn = g2[b + 256];
    const float r = 1.f / (1.f + __expf(-(ir + hr)));
    const float z = 1.f / (1.f + __expf(-(iz + hz)));
    const float n = tanhf(in + r * hn);
    const float hv = h[tid];
    h[tid] = (1.f - z) * n + z * hv;
}

extern "C" void kernel_launch(void* const* d_in, const int* in_sizes, int n_in,
                              void* d_out, int out_size, void* d_ws, size_t ws_size,
                              hipStream_t stream)
{
    const float* x     = (const float*)d_in[0];
    const int*   edges = (const int*)  d_in[1];   // [2, E] int32
    const float* W1    = (const float*)d_in[2];
    const float* b1    = (const float*)d_in[3];
    const float* Wconv = (const float*)d_in[4];   // [3,128,128]
    const float* Wih   = (const float*)d_in[5];   // [384,128]
    const float* Whh   = (const float*)d_in[6];   // [384,128]
    const float* bih   = (const float*)d_in[7];   // [384]
    const float* bhh   = (const float*)d_in[8];   // [384]
    const float* W2    = (const float*)d_in[9];   // [384,128]
    const float* b2    = (const float*)d_in[10];  // [384]
    float* out = (float*)d_out;

    const int N = in_sizes[0] / D;   // 100000
    const int E = in_sizes[1] / 2;   // 600000

    // workspace layout (floats): h[N*128] | agg[N*128] | g1[N*384] (aliases m[N*128]) | g2[N*384]
    float* h   = (float*)d_ws;
    float* agg = h   + (size_t)N * D;
    float* g1  = agg + (size_t)N * D;
    float* g2  = g1  + (size_t)N * 384;
    float* m   = g1;   // m dead before g1 is written

    const dim3 blk(256);
    const int mb = (N + 63) / 64;

    // h = relu(x @ W1^T + b1)
    gemm_k128<<<dim3(mb, 2), blk, 0, stream>>>(x, W1, b1, h, N, D, 0, 1);

    for (int l = 0; l < 3; ++l) {
        // m = h @ Wconv[l]^T
        gemm_k128<<<dim3(mb, 2), blk, 0, stream>>>(h, Wconv + (size_t)l * D * D,
                                                   nullptr, m, N, D, 0, 0);
        // agg = segment_sum(m[src], dst)
        hipMemsetAsync(agg, 0, (size_t)N * D * sizeof(float), stream);
        scatter_add<<<dim3((E * 32 + 255) / 256), blk, 0, stream>>>(m, edges, edges + E, agg, E, N);
        // gi = agg @ Wih^T + bih ; gh = h @ Whh^T + bhh
        gemm_k128<<<dim3(mb, 6), blk, 0, stream>>>(agg, Wih, bih, g1, N, 384, 0, 0);
        gemm_k128<<<dim3(mb, 6), blk, 0, stream>>>(h,   Whh, bhh, g2, N, 384, 0, 0);
        // h = GRU combine
        gru_combine<<<dim3((N * D + 255) / 256), blk, 0, stream>>>(g1, g2, h, N * D);
    }

    // out = relu(h) @ W2^T + b2
    gemm_k128<<<dim3(mb, 6), blk, 0, stream>>>(h, W2, b2, out, N, 384, 1, 0);
}

// Round 2
// 2579.024 us; speedup vs baseline: 2.1080x; 2.1080x over previous
//
#include <hip/hip_runtime.h>

#define D 128
#define SCAN_E 2048   // elements per scan block (256 thr x 8)

// ---------------- GEMM (unchanged from R1): C = act(A @ W^T + bias) ----------------
__global__ __launch_bounds__(256, 2)
void gemm_k128(const float* __restrict__ A, const float* __restrict__ W,
               const float* __restrict__ bias, float* __restrict__ C,
               int M, int NC, int reluA, int reluC)
{
    __shared__ float sA[64 * 128];
    __shared__ float sW[64 * 128];
    const int t  = threadIdx.x;
    const int m0 = blockIdx.x * 64;
    const int n0 = blockIdx.y * 64;

    {
        const int c4 = (t & 31) * 4;
        const int r  = t >> 5;
        #pragma unroll
        for (int i = 0; i < 8; ++i) {
            const int rr = r * 8 + i;
            const int gm = m0 + rr;
            float4 v = make_float4(0.f, 0.f, 0.f, 0.f);
            if (gm < M) v = *reinterpret_cast<const float4*>(A + (size_t)gm * D + c4);
            if (reluA) { v.x = fmaxf(v.x, 0.f); v.y = fmaxf(v.y, 0.f);
                         v.z = fmaxf(v.z, 0.f); v.w = fmaxf(v.w, 0.f); }
            const int cb = c4 ^ ((rr & 7) << 2);
            sA[rr * 128 + cb + 0] = v.x;
            sA[rr * 128 + cb + 1] = v.y;
            sA[rr * 128 + cb + 2] = v.z;
            sA[rr * 128 + cb + 3] = v.w;
        }
        #pragma unroll
        for (int i = 0; i < 8; ++i) {
            const int rr = r * 8 + i;
            float4 v = *reinterpret_cast<const float4*>(W + (size_t)(n0 + rr) * D + c4);
            const int cb = c4 ^ ((rr & 7) << 2);
            sW[rr * 128 + cb + 0] = v.x;
            sW[rr * 128 + cb + 1] = v.y;
            sW[rr * 128 + cb + 2] = v.z;
            sW[rr * 128 + cb + 3] = v.w;
        }
    }
    __syncthreads();

    const int tx = t & 15;
    const int ty = t >> 4;
    const int axor = (ty & 7) << 2;
    const int wxor = (tx & 7) << 2;

    float acc[4][4];
    #pragma unroll
    for (int i = 0; i < 4; ++i)
        #pragma unroll
        for (int j = 0; j < 4; ++j) acc[i][j] = 0.f;

    #pragma unroll 8
    for (int k = 0; k < D; ++k) {
        const int kA = k ^ axor;
        const int kW = k ^ wxor;
        float a0 = sA[(ty     ) * 128 + kA];
        float a1 = sA[(ty + 16) * 128 + kA];
        float a2 = sA[(ty + 32) * 128 + kA];
        float a3 = sA[(ty + 48) * 128 + kA];
        float w0 = sW[(tx     ) * 128 + kW];
        float w1 = sW[(tx + 16) * 128 + kW];
        float w2 = sW[(tx + 32) * 128 + kW];
        float w3 = sW[(tx + 48) * 128 + kW];
        acc[0][0] += a0 * w0; acc[0][1] += a0 * w1; acc[0][2] += a0 * w2; acc[0][3] += a0 * w3;
        acc[1][0] += a1 * w0; acc[1][1] += a1 * w1; acc[1][2] += a1 * w2; acc[1][3] += a1 * w3;
        acc[2][0] += a2 * w0; acc[2][1] += a2 * w1; acc[2][2] += a2 * w2; acc[2][3] += a2 * w3;
        acc[3][0] += a3 * w0; acc[3][1] += a3 * w1; acc[3][2] += a3 * w2; acc[3][3] += a3 * w3;
    }

    float bv[4] = {0.f, 0.f, 0.f, 0.f};
    if (bias) {
        bv[0] = bias[n0 + tx];      bv[1] = bias[n0 + tx + 16];
        bv[2] = bias[n0 + tx + 32]; bv[3] = bias[n0 + tx + 48];
    }
    #pragma unroll
    for (int i = 0; i < 4; ++i) {
        const int gm = m0 + ty + 16 * i;
        if (gm < M) {
            #pragma unroll
            for (int j = 0; j < 4; ++j) {
                float v = acc[i][j] + bv[j];
                if (reluC) v = fmaxf(v, 0.f);
                C[(size_t)gm * NC + n0 + tx + 16 * j] = v;
            }
        }
    }
}

// ---------------- CSR build: histogram -> 2-level exclusive scan -> fill ----------------
__global__ __launch_bounds__(256)
void count_dst(const int* __restrict__ dst, int* __restrict__ counts, int E, int N)
{
    const int e = blockIdx.x * 256 + threadIdx.x;
    if (e >= E) return;
    const int d = dst[e];
    if ((unsigned)d < (unsigned)N) atomicAdd(&counts[d], 1);
}

__global__ __launch_bounds__(256)
void scan_block(const int* __restrict__ counts, int* __restrict__ rowptr,
                int* __restrict__ partials, int N)
{
    __shared__ int sT[256];
    const int t = threadIdx.x;
    const int base = blockIdx.x * SCAN_E + t * 8;
    int v[8]; int s = 0;
    #pragma unroll
    for (int i = 0; i < 8; ++i) {
        const int idx = base + i;
        v[i] = (idx < N) ? counts[idx] : 0;
        s += v[i];
    }
    sT[t] = s;
    __syncthreads();
    for (int off = 1; off < 256; off <<= 1) {
        int x = (t >= off) ? sT[t - off] : 0;
        __syncthreads();
        sT[t] += x;
        __syncthreads();
    }
    if (t == 255) partials[blockIdx.x] = sT[255];
    int run = sT[t] - s;   // exclusive prefix for this thread within block
    #pragma unroll
    for (int i = 0; i < 8; ++i) {
        const int idx = base + i;
        if (idx < N) rowptr[idx] = run;
        run += v[i];
    }
}

__global__ void scan_partials(int* __restrict__ partials, int nb,
                              int* __restrict__ rowptr, int N)
{
    if (threadIdx.x == 0 && blockIdx.x == 0) {
        int run = 0;
        for (int i = 0; i < nb; ++i) { int c = partials[i]; partials[i] = run; run += c; }
        rowptr[N] = run;
    }
}

__global__ __launch_bounds__(256)
void add_offsets(int* __restrict__ rowptr, const int* __restrict__ partials,
                 int* __restrict__ cursor, int N)
{
    const int off  = partials[blockIdx.x];
    const int base = blockIdx.x * SCAN_E + threadIdx.x * 8;
    #pragma unroll
    for (int i = 0; i < 8; ++i) {
        const int idx = base + i;
        if (idx < N) { const int r = rowptr[idx] + off; rowptr[idx] = r; cursor[idx] = r; }
    }
}

__global__ __launch_bounds__(256)
void fill_csr(const int* __restrict__ src, const int* __restrict__ dst,
              int* __restrict__ cursor, int* __restrict__ eidx, int E, int N)
{
    const int e = blockIdx.x * 256 + threadIdx.x;
    if (e >= E) return;
    const int d = dst[e], s = src[e];
    if ((unsigned)d >= (unsigned)N || (unsigned)s >= (unsigned)N) return;
    const int slot = atomicAdd(&cursor[d], 1);
    eidx[slot] = s;
}

// ---------------- atomic-free gather: agg[n] = sum_{e in csr row n} m[eidx[e]] ----------------
__global__ __launch_bounds__(256)
void gather_sum(const float* __restrict__ m, const int* __restrict__ rowptr,
                const int* __restrict__ eidx, float* __restrict__ agg, int N)
{
    const int tid  = blockIdx.x * 256 + threadIdx.x;
    const int node = tid >> 5;
    const int lane = tid & 31;
    if (node >= N) return;
    const int beg = rowptr[node];
    const int end = rowptr[node + 1];
    float4 acc = make_float4(0.f, 0.f, 0.f, 0.f);
    for (int e = beg; e < end; ++e) {
        const int s = eidx[e];
        const float4 v = *reinterpret_cast<const float4*>(m + (size_t)s * D + lane * 4);
        acc.x += v.x; acc.y += v.y; acc.z += v.z; acc.w += v.w;
    }
    *reinterpret_cast<float4*>(agg + (size_t)node * D + lane * 4) = acc;
}

// ---------------- GRU elementwise combine ----------------
__global__ __launch_bounds__(256)
void gru_combine(const float* __restrict__ g1, const float* __restrict__ g2,
                 float* __restrict__ h, int total)
{
    const int tid = blockIdx.x * 256 + threadIdx.x;
    if (tid >= total) return;
    const int node = tid >> 7;
    const int c    = tid & 127;
    const size_t b = (size_t)node * 384 + c;
    const float ir = g1[b], iz = g1[b + 128], in = g1[b + 256];
    const float hr = g2[b], hz = g2[b + 128], hn = g2[b + 256];
    const float r = 1.f / (1.f + __expf(-(ir + hr)));
    const float z = 1.f / (1.f + __expf(-(iz + hz)));
    const float n = tanhf(in + r * hn);
    const float hv = h[tid];
    h[tid] = (1.f - z) * n + z * hv;
}

extern "C" void kernel_launch(void* const* d_in, const int* in_sizes, int n_in,
                              void* d_out, int out_size, void* d_ws, size_t ws_size,
                              hipStream_t stream)
{
    const float* x     = (const float*)d_in[0];
    const int*   edges = (const int*)  d_in[1];
    const float* W1    = (const float*)d_in[2];
    const float* b1    = (const float*)d_in[3];
    const float* Wconv = (const float*)d_in[4];
    const float* Wih   = (const float*)d_in[5];
    const float* Whh   = (const float*)d_in[6];
    const float* bih   = (const float*)d_in[7];
    const float* bhh   = (const float*)d_in[8];
    const float* W2    = (const float*)d_in[9];
    const float* b2    = (const float*)d_in[10];
    float* out = (float*)d_out;

    const int N = in_sizes[0] / D;   // 100000
    const int E = in_sizes[1] / 2;   // 600000

    // workspace layout (floats): h[N*128] | agg[N*128] | g1[N*384] (m aliases g1) | g2[N*384]
    // then (ints): counts[N] | rowptr[N+1] | cursor[N] | partials[64] | eidx[E]
    float* h   = (float*)d_ws;
    float* agg = h   + (size_t)N * D;
    float* g1  = agg + (size_t)N * D;
    float* g2  = g1  + (size_t)N * 384;
    float* m   = g1;
    int* counts   = (int*)(g2 + (size_t)N * 384);
    int* rowptr   = counts + N;
    int* cursor   = rowptr + N + 1;
    int* partials = cursor + N;
    int* eidx     = partials + 64;

    const int*  src = edges;
    const int*  dst = edges + E;

    const dim3 blk(256);
    const int mb = (N + 63) / 64;
    const int nb = (N + SCAN_E - 1) / SCAN_E;   // 49 scan blocks

    // ---- build CSR of edges bucketed by dst (once; reused by all 3 layers) ----
    hipMemsetAsync(counts, 0, (size_t)N * sizeof(int), stream);
    count_dst<<<dim3((E + 255) / 256), blk, 0, stream>>>(dst, counts, E, N);
    scan_block<<<dim3(nb), blk, 0, stream>>>(counts, rowptr, partials, N);
    scan_partials<<<dim3(1), dim3(64), 0, stream>>>(partials, nb, rowptr, N);
    add_offsets<<<dim3(nb), blk, 0, stream>>>(rowptr, partials, cursor, N);
    fill_csr<<<dim3((E + 255) / 256), blk, 0, stream>>>(src, dst, cursor, eidx, E, N);

    // ---- h = relu(x @ W1^T + b1) ----
    gemm_k128<<<dim3(mb, 2), blk, 0, stream>>>(x, W1, b1, h, N, D, 0, 1);

    for (int l = 0; l < 3; ++l) {
        gemm_k128<<<dim3(mb, 2), blk, 0, stream>>>(h, Wconv + (size_t)l * D * D,
                                                   nullptr, m, N, D, 0, 0);
        gather_sum<<<dim3((N * 32 + 255) / 256), blk, 0, stream>>>(m, rowptr, eidx, agg, N);
        gemm_k128<<<dim3(mb, 6), blk, 0, stream>>>(agg, Wih, bih, g1, N, 384, 0, 0);
        gemm_k128<<<dim3(mb, 6), blk, 0, stream>>>(h,   Whh, bhh, g2, N, 384, 0, 0);
        gru_combine<<<dim3((N * D + 255) / 256), blk, 0, stream>>>(g1, g2, h, N * D);
    }

    gemm_k128<<<dim3(mb, 6), blk, 0, stream>>>(h, W2, b2, out, N, 384, 1, 0);
}

// Round 3
// 1318.315 us; speedup vs baseline: 4.1238x; 1.9563x over previous
//
#include <hip/hip_runtime.h>

#define D 128
#define SCAN_E 2048

typedef __attribute__((ext_vector_type(8))) short short8;
typedef __attribute__((ext_vector_type(4))) float floatx4;

__device__ __forceinline__ unsigned short f2bf(float x) {
    union { float f; unsigned u; } v; v.f = x;
    unsigned r = v.u + 0x7FFFu + ((v.u >> 16) & 1u);
    return (unsigned short)(r >> 16);
}
__device__ __forceinline__ float bf2f(unsigned short h) {
    union { float f; unsigned u; } v; v.u = ((unsigned)h) << 16;
    return v.f;
}
__device__ __forceinline__ void split2(float x, unsigned short& hi, unsigned short& lo) {
    hi = f2bf(x);
    lo = f2bf(x - bf2f(hi));
}
__device__ __forceinline__ void load16(const void* g, void* l) {
    __builtin_amdgcn_global_load_lds((const __attribute__((address_space(1))) unsigned*)g,
                                     (__attribute__((address_space(3))) unsigned*)l, 16, 0, 0);
}

// ---------- split-precision bf16 MFMA GEMM ----------
// C[M,NC] = A @ W^T (+bias) where A given as bf16 planes [M][256] = [Ah|Al] (fp32-split)
// and W given pre-split as [NC][384] = [Wh|Wh|Wl].  Effective K=384 bf16:
//   k in [0,128):  Ah*Wh ; [128,256): Al*Wh ; [256,384): Ah*Wl   (error <= 2^-17)
// 128x128 tile, 4 waves (each 64x64), global_load_lds staging, 16x16x32 bf16 MFMA.
__global__ __launch_bounds__(256, 2)
void gemm_split(const unsigned short* __restrict__ Apl,
                const unsigned short* __restrict__ Wsp,
                const float* __restrict__ bias,
                float* __restrict__ Cf,            // fp32 out (or null)
                unsigned short* __restrict__ Cpl,  // bf16-plane out [M][256] (or null; NC==128 only)
                int M, int NC, int relu)
{
    __shared__ unsigned short sA[128 * 64];
    __shared__ unsigned short sW[128 * 64];
    const int t    = threadIdx.x;
    const int lane = t & 63;
    const int wv   = t >> 6;
    const int m0   = blockIdx.x * 128;
    const int n0   = blockIdx.y * 128;

    const int scolb = (lane & 7) * 16;     // byte offset within 128-B row chunk
    const int lrow  = lane >> 3;           // 0..7

    floatx4 acc[4][4];
    #pragma unroll
    for (int i = 0; i < 4; ++i)
        #pragma unroll
        for (int j = 0; j < 4; ++j)
            #pragma unroll
            for (int r = 0; r < 4; ++r) acc[i][j][r] = 0.f;

    for (int kk = 0; kk < 6; ++kk) {
        const int akb = ((kk < 4) ? kk : kk - 4) * 128;  // A-plane k-byte offset (row is 512 B)
        const int wkb = kk * 128;                        // W k-byte offset (row is 768 B)
        #pragma unroll
        for (int i = 0; i < 4; ++i) {
            const int rr = (wv * 4 + i) * 8 + lrow;      // 0..127 tile row
            int am = m0 + rr; if (am > M - 1) am = M - 1;
            load16((const char*)Apl + (size_t)am * 512 + akb + scolb,
                   (char*)sA + (size_t)(wv * 4 + i) * 1024);
            load16((const char*)Wsp + (size_t)(n0 + rr) * 768 + wkb + scolb,
                   (char*)sW + (size_t)(wv * 4 + i) * 1024);
        }
        __syncthreads();
        const int lane15 = lane & 15;
        const int quad   = lane >> 4;
        #pragma unroll
        for (int ks = 0; ks < 2; ++ks) {
            short8 a[4], b[4];
            const int koff = ks * 32 + quad * 8;
            #pragma unroll
            for (int i = 0; i < 4; ++i)
                a[i] = *(const short8*)(sA + ((wv >> 1) * 64 + i * 16 + lane15) * 64 + koff);
            #pragma unroll
            for (int j = 0; j < 4; ++j)
                b[j] = *(const short8*)(sW + ((wv & 1) * 64 + j * 16 + lane15) * 64 + koff);
            #pragma unroll
            for (int i = 0; i < 4; ++i)
                #pragma unroll
                for (int j = 0; j < 4; ++j)
                    acc[i][j] = __builtin_amdgcn_mfma_f32_16x16x32_bf16(a[i], b[j], acc[i][j], 0, 0, 0);
        }
        __syncthreads();
    }

    const int lane15 = lane & 15;
    const int quad   = lane >> 4;
    #pragma unroll
    for (int i = 0; i < 4; ++i) {
        #pragma unroll
        for (int r = 0; r < 4; ++r) {
            const int m = m0 + (wv >> 1) * 64 + i * 16 + quad * 4 + r;
            if (m >= M) continue;
            #pragma unroll
            for (int j = 0; j < 4; ++j) {
                const int n = n0 + (wv & 1) * 64 + j * 16 + lane15;
                float v = acc[i][j][r] + (bias ? bias[n] : 0.f);
                if (relu) v = fmaxf(v, 0.f);
                if (Cf) Cf[(size_t)m * NC + n] = v;
                if (Cpl) {
                    unsigned short hi, lo; split2(v, hi, lo);
                    Cpl[(size_t)m * 256 + n] = hi;
                    Cpl[(size_t)m * 256 + 128 + n] = lo;
                }
            }
        }
    }
}

// ---------- weight / activation splitting ----------
__global__ __launch_bounds__(256)
void split_wt(const float* __restrict__ W, unsigned short* __restrict__ out, int total)
{
    const int tid = blockIdx.x * 256 + threadIdx.x;
    if (tid >= total) return;
    const int n = tid >> 7, k = tid & 127;
    unsigned short hi, lo; split2(W[tid], hi, lo);
    out[(size_t)n * 384 + k]       = hi;
    out[(size_t)n * 384 + 128 + k] = hi;
    out[(size_t)n * 384 + 256 + k] = lo;
}

__global__ __launch_bounds__(256)
void split_act(const float* __restrict__ A, unsigned short* __restrict__ out, int total)
{
    const int tid = blockIdx.x * 256 + threadIdx.x;
    if (tid >= total) return;
    const int n = tid >> 7, k = tid & 127;
    unsigned short hi, lo; split2(A[tid], hi, lo);
    out[(size_t)n * 256 + k]       = hi;
    out[(size_t)n * 256 + 128 + k] = lo;
}

// ---------- CSR build ----------
__global__ __launch_bounds__(256)
void count_dst(const int* __restrict__ dst, int* __restrict__ counts, int E, int N)
{
    const int e = blockIdx.x * 256 + threadIdx.x;
    if (e >= E) return;
    const int d = dst[e];
    if ((unsigned)d < (unsigned)N) atomicAdd(&counts[d], 1);
}

__global__ __launch_bounds__(256)
void scan_block(const int* __restrict__ counts, int* __restrict__ rowptr,
                int* __restrict__ partials, int N)
{
    __shared__ int sT[256];
    const int t = threadIdx.x;
    const int base = blockIdx.x * SCAN_E + t * 8;
    int v[8]; int s = 0;
    #pragma unroll
    for (int i = 0; i < 8; ++i) {
        const int idx = base + i;
        v[i] = (idx < N) ? counts[idx] : 0;
        s += v[i];
    }
    sT[t] = s;
    __syncthreads();
    for (int off = 1; off < 256; off <<= 1) {
        int x = (t >= off) ? sT[t - off] : 0;
        __syncthreads();
        sT[t] += x;
        __syncthreads();
    }
    if (t == 255) partials[blockIdx.x] = sT[255];
    int run = sT[t] - s;
    #pragma unroll
    for (int i = 0; i < 8; ++i) {
        const int idx = base + i;
        if (idx < N) rowptr[idx] = run;
        run += v[i];
    }
}

__global__ void scan_partials(int* __restrict__ partials, int nb,
                              int* __restrict__ rowptr, int N)
{
    if (threadIdx.x == 0 && blockIdx.x == 0) {
        int run = 0;
        for (int i = 0; i < nb; ++i) { int c = partials[i]; partials[i] = run; run += c; }
        rowptr[N] = run;
    }
}

__global__ __launch_bounds__(256)
void add_offsets(int* __restrict__ rowptr, const int* __restrict__ partials,
                 int* __restrict__ cursor, int N)
{
    const int off  = partials[blockIdx.x];
    const int base = blockIdx.x * SCAN_E + threadIdx.x * 8;
    #pragma unroll
    for (int i = 0; i < 8; ++i) {
        const int idx = base + i;
        if (idx < N) { const int r = rowptr[idx] + off; rowptr[idx] = r; cursor[idx] = r; }
    }
}

__global__ __launch_bounds__(256)
void fill_csr(const int* __restrict__ src, const int* __restrict__ dst,
              int* __restrict__ cursor, int* __restrict__ eidx, int E, int N)
{
    const int e = blockIdx.x * 256 + threadIdx.x;
    if (e >= E) return;
    const int d = dst[e], s = src[e];
    if ((unsigned)d >= (unsigned)N || (unsigned)s >= (unsigned)N) return;
    const int slot = atomicAdd(&cursor[d], 1);
    eidx[slot] = s;
}

// ---------- gather with split epilogue: aggpl = planes(segment_sum(m[src])) ----------
__global__ __launch_bounds__(256)
void gather_sum_pl(const float* __restrict__ m, const int* __restrict__ rowptr,
                   const int* __restrict__ eidx, unsigned short* __restrict__ aggpl, int N)
{
    const int tid  = blockIdx.x * 256 + threadIdx.x;
    const int node = tid >> 5;
    const int lane = tid & 31;
    if (node >= N) return;
    const int beg = rowptr[node];
    const int end = rowptr[node + 1];
    float4 acc = make_float4(0.f, 0.f, 0.f, 0.f);
    for (int e = beg; e < end; ++e) {
        const int s = eidx[e];
        const float4 v = *reinterpret_cast<const float4*>(m + (size_t)s * D + lane * 4);
        acc.x += v.x; acc.y += v.y; acc.z += v.z; acc.w += v.w;
    }
    ushort4 hi, lo;
    split2(acc.x, hi.x, lo.x); split2(acc.y, hi.y, lo.y);
    split2(acc.z, hi.z, lo.z); split2(acc.w, hi.w, lo.w);
    *reinterpret_cast<ushort4*>(aggpl + (size_t)node * 256 + lane * 4)       = hi;
    *reinterpret_cast<ushort4*>(aggpl + (size_t)node * 256 + 128 + lane * 4) = lo;
}

// ---------- GRU combine; h carried as bf16 planes (exact to 2^-17) ----------
__global__ __launch_bounds__(256)
void gru_combine_pl(const float* __restrict__ g1, const float* __restrict__ g2,
                    unsigned short* __restrict__ hpl, int total, int relu)
{
    const int tid = blockIdx.x * 256 + threadIdx.x;
    if (tid >= total) return;
    const int node = tid >> 7;
    const int c    = tid & 127;
    const size_t b = (size_t)node * 384 + c;
    const float ir = g1[b], iz = g1[b + 128], in = g1[b + 256];
    const float hr = g2[b], hz = g2[b + 128], hn = g2[b + 256];
    const size_t hb = (size_t)node * 256 + c;
    const float h = bf2f(hpl[hb]) + bf2f(hpl[hb + 128]);
    const float r = 1.f / (1.f + __expf(-(ir + hr)));
    const float z = 1.f / (1.f + __expf(-(iz + hz)));
    const float n = tanhf(in + r * hn);
    float v = (1.f - z) * n + z * h;
    if (relu) v = fmaxf(v, 0.f);
    unsigned short hi, lo; split2(v, hi, lo);
    hpl[hb]       = hi;
    hpl[hb + 128] = lo;
}

extern "C" void kernel_launch(void* const* d_in, const int* in_sizes, int n_in,
                              void* d_out, int out_size, void* d_ws, size_t ws_size,
                              hipStream_t stream)
{
    const float* x     = (const float*)d_in[0];
    const int*   edges = (const int*)  d_in[1];
    const float* W1    = (const float*)d_in[2];
    const float* b1    = (const float*)d_in[3];
    const float* Wconv = (const float*)d_in[4];
    const float* Wih   = (const float*)d_in[5];
    const float* Whh   = (const float*)d_in[6];
    const float* bih   = (const float*)d_in[7];
    const float* bhh   = (const float*)d_in[8];
    const float* W2    = (const float*)d_in[9];
    const float* b2    = (const float*)d_in[10];
    float* out = (float*)d_out;

    const int N = in_sizes[0] / D;   // 100000
    const int E = in_sizes[1] / 2;   // 600000

    // ---- workspace layout (≈363 MB) ----
    char* base = (char*)d_ws;
    const size_t szHpl = (size_t)N * 256 * 2;   // h planes
    const size_t szG   = (size_t)N * 384 * 4;   // g1 / g2
    unsigned short* h_pl = (unsigned short*)base;
    float* g1 = (float*)(base + szHpl);
    float* g2 = (float*)(base + szHpl + szG);
    unsigned short* Wsp = (unsigned short*)(base + szHpl + 2 * szG);
    const size_t szW = (size_t)1664 * 384 * 2;  // 7 split weight matrices
    int* rowptr   = (int*)(base + szHpl + 2 * szG + szW);
    int* counts   = rowptr + N + 1;             // doubles as cursor
    int* partials = counts + N;
    int* eidx     = partials + 64;
    // aliases (lifetimes disjoint): x-planes & m live in g1; agg-planes in g2
    unsigned short* x_pl   = (unsigned short*)g1;
    float*          m      = (float*)g1;
    unsigned short* agg_pl = (unsigned short*)g2;

    unsigned short* W1s  = Wsp;
    unsigned short* Wcs0 = Wsp + (size_t)128 * 384;
    unsigned short* Wihs = Wsp + (size_t)512 * 384;
    unsigned short* Whhs = Wsp + (size_t)896 * 384;
    unsigned short* W2s  = Wsp + (size_t)1280 * 384;

    const int* src = edges;
    const int* dst = edges + E;

    const dim3 blk(256);
    const int mb = (N + 127) / 128;                 // 782
    const int nb = (N + SCAN_E - 1) / SCAN_E;

    // ---- split weights (tiny) & x ----
    split_wt<<<dim3(128 * 128 / 256), blk, 0, stream>>>(W1, W1s, 128 * 128);
    for (int l = 0; l < 3; ++l)
        split_wt<<<dim3(128 * 128 / 256), blk, 0, stream>>>(Wconv + (size_t)l * 128 * 128,
                                                            Wcs0 + (size_t)l * 128 * 384, 128 * 128);
    split_wt<<<dim3(384 * 128 / 256), blk, 0, stream>>>(Wih, Wihs, 384 * 128);
    split_wt<<<dim3(384 * 128 / 256), blk, 0, stream>>>(Whh, Whhs, 384 * 128);
    split_wt<<<dim3(384 * 128 / 256), blk, 0, stream>>>(W2,  W2s,  384 * 128);
    split_act<<<dim3((N * 128 + 255) / 256), blk, 0, stream>>>(x, x_pl, N * 128);

    // ---- build CSR (dst-bucketed) once ----
    hipMemsetAsync(counts, 0, (size_t)N * sizeof(int), stream);
    count_dst<<<dim3((E + 255) / 256), blk, 0, stream>>>(dst, counts, E, N);
    scan_block<<<dim3(nb), blk, 0, stream>>>(counts, rowptr, partials, N);
    scan_partials<<<dim3(1), dim3(64), 0, stream>>>(partials, nb, rowptr, N);
    add_offsets<<<dim3(nb), blk, 0, stream>>>(rowptr, partials, counts, N);
    fill_csr<<<dim3((E + 255) / 256), blk, 0, stream>>>(src, dst, counts, eidx, E, N);

    // ---- h = relu(x @ W1^T + b1), stored as planes only ----
    gemm_split<<<dim3(mb, 1), blk, 0, stream>>>(x_pl, W1s, b1, nullptr, h_pl, N, 128, 1);

    for (int l = 0; l < 3; ++l) {
        gemm_split<<<dim3(mb, 1), blk, 0, stream>>>(h_pl, Wcs0 + (size_t)l * 128 * 384,
                                                    nullptr, m, nullptr, N, 128, 0);
        gather_sum_pl<<<dim3((N * 32 + 255) / 256), blk, 0, stream>>>(m, rowptr, eidx, agg_pl, N);
        gemm_split<<<dim3(mb, 3), blk, 0, stream>>>(agg_pl, Wihs, bih, g1, nullptr, N, 384, 0);
        gemm_split<<<dim3(mb, 3), blk, 0, stream>>>(h_pl,   Whhs, bhh, g2, nullptr, N, 384, 0);
        gru_combine_pl<<<dim3((N * 128 + 255) / 256), blk, 0, stream>>>(g1, g2, h_pl, N * 128, l == 2);
    }

    // ---- out = relu(h) @ W2^T + b2 (relu already in planes) ----
    gemm_split<<<dim3(mb, 3), blk, 0, stream>>>(h_pl, W2s, b2, out, nullptr, N, 384, 0);
}